// Round 9
// baseline (278.084 us; speedup 1.0000x reference)
//
#include <hip/hip_runtime.h>
#include <math.h>

typedef __bf16 bf16x8 __attribute__((ext_vector_type(8)));
typedef unsigned short u16x8 __attribute__((ext_vector_type(8)));
typedef float f32x4 __attribute__((ext_vector_type(4)));

namespace {
constexpr int kB   = 32;
constexpr int kC   = 64;
constexpr int kT   = 8192;
constexpr int kOUT = 129;
constexpr int kKK  = 1024;   // K*K
constexpr int kNKC = 8;      // k-chunks in phase GEMM (128 f each)
constexpr int kOP  = 144;    // o rows padded to 144 (9 m-tiles, guard-free loads)
}

__device__ inline float sin2pi(float r) {  // r in revolutions, [0,1)
  float o; asm("v_sin_f32 %0, %1" : "=v"(o) : "v"(r)); return o;
}
__device__ inline float cos2pi(float r) {
  float o; asm("v_cos_f32 %0, %1" : "=v"(o) : "v"(r)); return o;
}
__device__ inline unsigned short f2bf_rne(float f) {
  unsigned int u = __builtin_bit_cast(unsigned int, f);
  return (unsigned short)((u + 0x7fffu + ((u >> 16) & 1u)) >> 16);
}
__device__ inline float bf2f(unsigned short h) {
  return __builtin_bit_cast(float, (unsigned int)h << 16);
}
__device__ inline void split8(const float* v, bf16x8& hi, bf16x8& lo) {
  u16x8 h, l;
#pragma unroll
  for (int j = 0; j < 8; ++j) {
    const unsigned short hh = f2bf_rne(v[j]);
    h[j] = hh;
    l[j] = f2bf_rne(v[j] - bf2f(hh));
  }
  hi = __builtin_bit_cast(bf16x8, h);
  lo = __builtin_bit_cast(bf16x8, l);
}
__device__ inline bf16x8 ldbf8(const unsigned short* p) {
  return __builtin_bit_cast(bf16x8, *reinterpret_cast<const u16x8*>(p));
}

// ---------------------------------------------------------------------------
// K0z: split z -> bf16 hi/lo, layout [fb=0..127][o=0..143][fj=0..7]
// (o padded with zeros so the phase GEMM needs no row guards).
// ---------------------------------------------------------------------------
__global__ __launch_bounds__(256) void sa_split_z(
    const float* __restrict__ z_real, const float* __restrict__ z_imag,
    unsigned short* __restrict__ zrh, unsigned short* __restrict__ zrl,
    unsigned short* __restrict__ zih, unsigned short* __restrict__ zil)
{
  const int i = blockIdx.x * 256 + threadIdx.x;
  if (i >= 128 * kOP * 8) return;
  const int fj = i & 7;
  const int o  = (i >> 3) % kOP;
  const int fb = i / (kOP * 8);
  const int f  = fb * 8 + fj;
  float vr = 0.f, vi = 0.f;
  if (o < kOUT) {
    vr = z_real[(size_t)o * kKK + f];
    vi = z_imag[(size_t)o * kKK + f];
  }
  unsigned short h = f2bf_rne(vr);
  zrh[i] = h; zrl[i] = f2bf_rne(vr - bf2f(h));
  h = f2bf_rne(vi);
  zih[i] = h; zil[i] = f2bf_rne(vi - bf2f(h));
}

// ---------------------------------------------------------------------------
// K0c: materialize split-bf16 cis tables, layout [b][fb=0..127][c=0..63][fj].
// ---------------------------------------------------------------------------
__global__ __launch_bounds__(256) void sa_cis(
    const float* __restrict__ positions,
    unsigned short* __restrict__ csh, unsigned short* __restrict__ csl,
    unsigned short* __restrict__ snh, unsigned short* __restrict__ snl)
{
  const int i = blockIdx.x * 256 + threadIdx.x;   // < 32*128*64*8 = 2097152
  const int fj = i & 7;
  const int c  = (i >> 3) & 63;
  const int fb = (i >> 9) & 127;
  const int b  = i >> 16;
  const int f  = fb * 8 + fj;
  const float2 p = reinterpret_cast<const float2*>(positions)[b * kC + c];
  const float kf = (float)((f & 31) + 1);   // coef_k = (f % 32) + 1
  const float lf = (float)((f >> 5) + 1);   // coef_l = (f / 32) + 1
  // match reference rounding: fl(fl(x*k) + fl(y*l)); trig in revolutions
  const float w = __fadd_rn(__fmul_rn(p.x, kf), __fmul_rn(p.y, lf));
  const float r = w - floorf(w);
  const float cs = cos2pi(r);
  const float sn = sin2pi(r);
  unsigned short h = f2bf_rne(cs);
  csh[i] = h; csl[i] = f2bf_rne(cs - bf2f(h));
  h = f2bf_rne(sn);
  snh[i] = h; snl[i] = f2bf_rne(sn - bf2f(h));
}

// ---------------------------------------------------------------------------
// K1: part[kc][b][o][c] = sum_{f in chunk} z[o,f]*cis[f,c] -- pure bf16 MFMA
// (split hi/lo both operands, lo*lo dropped). Grid = 32b x 8kc x 2mh.
// MFMA map (HW-verified r4): A row=lane&15,k=8*(lane>>4)+j; B col=lane&15;
// D col=lane&15,row=(lane>>4)*4+r.
// ---------------------------------------------------------------------------
__global__ __launch_bounds__(256) void sa_phase_gemm(
    const unsigned short* __restrict__ zrh, const unsigned short* __restrict__ zrl,
    const unsigned short* __restrict__ zih, const unsigned short* __restrict__ zil,
    const unsigned short* __restrict__ csh, const unsigned short* __restrict__ csl,
    const unsigned short* __restrict__ snh, const unsigned short* __restrict__ snl,
    float* __restrict__ part)
{
  const int bid = blockIdx.x;
  const int b   = bid & 31;
  const int kc  = (bid >> 5) & 7;
  const int mh  = bid >> 8;            // 0: m-tiles 0..4, 1: m-tiles 5..8
  const int w    = threadIdx.x >> 6;
  const int lane = threadIdx.x & 63;
  const int cg   = lane >> 4;
  const int cl   = lane & 15;
  const int c    = w * 16 + cl;

  // B-frags (cis) for 4 k-steps
  bf16x8 BcH[4], BcL[4], BsH[4], BsL[4];
#pragma unroll
  for (int ks = 0; ks < 4; ++ks) {
    const size_t off = ((size_t)(b * 128 + kc * 16 + ks * 4 + cg) * kC + c) * 8;
    BcH[ks] = ldbf8(csh + off);
    BcL[ks] = ldbf8(csl + off);
    BsH[ks] = ldbf8(snh + off);
    BsL[ks] = ldbf8(snl + off);
  }

  const int nm  = mh ? 4 : 5;
  const int ob0 = mh * 80;

#pragma unroll
  for (int m = 0; m < 5; ++m) {
    if (m < nm) {
      const int ob = ob0 + m * 16;
      const int oa = ob + cl;          // padded rows -> no guard
      f32x4 acc = {0.f, 0.f, 0.f, 0.f};
#pragma unroll
      for (int ks = 0; ks < 4; ++ks) {
        const size_t zo = ((size_t)(kc * 16 + ks * 4 + cg) * kOP + oa) * 8;
        const bf16x8 ArH = ldbf8(zrh + zo);
        const bf16x8 ArL = ldbf8(zrl + zo);
        const bf16x8 AiH = ldbf8(zih + zo);
        const bf16x8 AiL = ldbf8(zil + zo);
        acc = __builtin_amdgcn_mfma_f32_16x16x32_bf16(ArH, BcH[ks], acc, 0, 0, 0);
        acc = __builtin_amdgcn_mfma_f32_16x16x32_bf16(ArH, BcL[ks], acc, 0, 0, 0);
        acc = __builtin_amdgcn_mfma_f32_16x16x32_bf16(ArL, BcH[ks], acc, 0, 0, 0);
        acc = __builtin_amdgcn_mfma_f32_16x16x32_bf16(AiH, BsH[ks], acc, 0, 0, 0);
        acc = __builtin_amdgcn_mfma_f32_16x16x32_bf16(AiH, BsL[ks], acc, 0, 0, 0);
        acc = __builtin_amdgcn_mfma_f32_16x16x32_bf16(AiL, BsH[ks], acc, 0, 0, 0);
      }
#pragma unroll
      for (int r = 0; r < 4; ++r) {
        const int o = ob + cg * 4 + r;
        if (o < kOUT)
          part[(((size_t)kc * kB + b) * kOUT + o) * kC + c] = acc[r];
      }
    }
  }
}

// ---------------------------------------------------------------------------
// K2: reduce f32 partials, mask, softmax over c. Emits split-bf16 attn into a
// PADDED [b][144][64] layout (rows 129..143 zeroed) so the apply kernel can
// load A-fragments straight from global with no guards and no LDS.
// grid = 32*144/4 = 1152 blocks of 256 (one wave per padded row).
// ---------------------------------------------------------------------------
__global__ __launch_bounds__(256) void sa_softmax(
    const float* __restrict__ part,
    const float* __restrict__ positions,
    const int*   __restrict__ drop_idx,
    unsigned short* __restrict__ a_hi,   // [b][144][64]
    unsigned short* __restrict__ a_lo)
{
  const int bop = blockIdx.x * 4 + (threadIdx.x >> 6);  // < 32*144
  const int b  = bop / kOP;
  const int o  = bop - b * kOP;
  const int c  = threadIdx.x & 63;

  if (o >= kOUT) {   // padding rows: zero
    a_hi[(size_t)bop * kC + c] = 0;
    a_lo[(size_t)bop * kC + c] = 0;
    return;
  }

  float a = 0.f;
#pragma unroll
  for (int fc = 0; fc < kNKC; ++fc)
    a += part[(((size_t)fc * kB + b) * kOUT + o) * kC + c];

  const float2 p  = reinterpret_cast<const float2*>(positions)[b * kC + c];
  const int    di = drop_idx[b];
  const float2 pd = reinterpret_cast<const float2*>(positions)[b * kC + di];
  const float dx = p.x - pd.x;
  const float dy = p.y - pd.y;
  const float d2 = __fadd_rn(__fmul_rn(dx, dx), __fmul_rn(dy, dy));
  if (d2 < 0.1f) a = -1e9f;

  float m = a;
#pragma unroll
  for (int off = 32; off; off >>= 1) m = fmaxf(m, __shfl_xor(m, off));
  const float e = expf(a - m);
  float s = e;
#pragma unroll
  for (int off = 32; off; off >>= 1) s += __shfl_xor(s, off);

  const float att = e / s;
  const unsigned short h = f2bf_rne(att);
  a_hi[(size_t)bop * kC + c] = h;
  a_lo[(size_t)bop * kC + c] = f2bf_rne(att - bf2f(h));
}

// ---------------------------------------------------------------------------
// K3: out[b,o,t] = sum_c attn[b,o,c] * X[b,c,t] via bf16 MFMA (Ah*Xh + Ah*Xl
// + Al*Xh). OCCUPANCY-FIRST: no LDS, no syncthreads, 1 n-tile (16 t) per
// wave, two independent 3-deep MFMA chains. A-frags read per-m from the
// padded global attn (L2-resident, 1KB/inst in 16x64B segments).
// grid = 32b x 128tc (64-t chunk) x 4 waves. Target ~5 waves/SIMD.
// ---------------------------------------------------------------------------
__global__ __launch_bounds__(256) void sa_apply_mfma(
    const float* __restrict__ X,
    const unsigned short* __restrict__ a_hi,   // [b][144][64]
    const unsigned short* __restrict__ a_lo,
    float* __restrict__ out)
{
  const int b    = blockIdx.x >> 7;
  const int tc   = blockIdx.x & 127;
  const int wave = threadIdx.x >> 6;
  const int lane = threadIdx.x & 63;
  const int cl   = lane & 15;
  const int cg   = lane >> 4;                 // k-group 0..3
  const int t    = tc * 64 + wave * 16 + cl;  // this wave's n-tile column

  // X frag (B operand): k = c = slice*32 + cg*8 + j
  const float* Xb = X + (size_t)b * kC * kT;
  float xv[16];
#pragma unroll
  for (int s2 = 0; s2 < 2; ++s2)
#pragma unroll
    for (int j = 0; j < 8; ++j)
      xv[s2 * 8 + j] = Xb[(size_t)(s2 * 32 + cg * 8 + j) * kT + t];

  bf16x8 Xh0, Xl0, Xh1, Xl1;
  split8(xv,     Xh0, Xl0);
  split8(xv + 8, Xh1, Xl1);

  const unsigned short* Ah = a_hi + (size_t)b * kOP * kC;
  const unsigned short* Al = a_lo + (size_t)b * kOP * kC;
  float* outb = out + (size_t)b * kOUT * kT;

#pragma unroll 3
  for (int m = 0; m < 9; ++m) {
    const int row = m * 16 + cl;              // A row this lane loads
    const size_t ra = (size_t)row * kC + cg * 8;
    const bf16x8 Ah0 = ldbf8(Ah + ra);        // c slice 0..31
    const bf16x8 Ah1 = ldbf8(Ah + ra + 32);   // c slice 32..63
    const bf16x8 Al0 = ldbf8(Al + ra);
    const bf16x8 Al1 = ldbf8(Al + ra + 32);

    // two independent 3-deep chains (slice0 -> p, slice1 -> q)
    f32x4 p = {0.f, 0.f, 0.f, 0.f};
    f32x4 q = {0.f, 0.f, 0.f, 0.f};
    p = __builtin_amdgcn_mfma_f32_16x16x32_bf16(Ah0, Xh0, p, 0, 0, 0);
    q = __builtin_amdgcn_mfma_f32_16x16x32_bf16(Ah1, Xh1, q, 0, 0, 0);
    p = __builtin_amdgcn_mfma_f32_16x16x32_bf16(Al0, Xh0, p, 0, 0, 0);
    q = __builtin_amdgcn_mfma_f32_16x16x32_bf16(Al1, Xh1, q, 0, 0, 0);
    p = __builtin_amdgcn_mfma_f32_16x16x32_bf16(Ah0, Xl0, p, 0, 0, 0);
    q = __builtin_amdgcn_mfma_f32_16x16x32_bf16(Ah1, Xl1, q, 0, 0, 0);

#pragma unroll
    for (int r = 0; r < 4; ++r) {
      const int o = m * 16 + cg * 4 + r;
      if (o < kOUT)
        outb[(size_t)o * kT + t] = p[r] + q[r];
    }
  }
}

// ---------------------------------------------------------------------------
extern "C" void kernel_launch(void* const* d_in, const int* in_sizes, int n_in,
                              void* d_out, int out_size, void* d_ws, size_t ws_size,
                              hipStream_t stream) {
  (void)in_sizes; (void)n_in; (void)out_size; (void)ws_size;
  const float* X         = (const float*)d_in[0];
  const float* positions = (const float*)d_in[1];
  const int*   drop_idx  = (const int*)d_in[2];
  const float* z_real    = (const float*)d_in[3];
  const float* z_imag    = (const float*)d_in[4];
  float* out = (float*)d_out;

  // workspace layout (~27.7 MB)
  char* wsb = (char*)d_ws;
  float* part = (float*)wsb;                                    // 8,454,144 B
  unsigned short* ahi = (unsigned short*)(wsb + 8454144);       // [32][144][64] 589,824 B
  unsigned short* alo = ahi + (size_t)kB * kOP * kC;            // 589,824 B
  unsigned short* zrh = alo + (size_t)kB * kOP * kC;            // 4 x 294,912 B
  unsigned short* zrl = zrh + 147456;
  unsigned short* zih = zrl + 147456;
  unsigned short* zil = zih + 147456;
  unsigned short* csh = zil + 147456;                           // 4 x 4,194,304 B
  unsigned short* csl = csh + 2097152;
  unsigned short* snh = csl + 2097152;
  unsigned short* snl = snh + 2097152;

  sa_split_z<<<576, 256, 0, stream>>>(z_real, z_imag, zrh, zrl, zih, zil);
  sa_cis<<<8192, 256, 0, stream>>>(positions, csh, csl, snh, snl);
  sa_phase_gemm<<<kB * kNKC * 2, 256, 0, stream>>>(zrh, zrl, zih, zil,
                                                   csh, csl, snh, snl, part);
  sa_softmax<<<kB * kOP / 4, 256, 0, stream>>>(part, positions, drop_idx, ahi, alo);
  sa_apply_mfma<<<kB * 128, 256, 0, stream>>>(X, ahi, alo, out);
}

// Round 12
// 238.187 us; speedup vs baseline: 1.1675x; 1.1675x over previous
//
#include <hip/hip_runtime.h>
#include <math.h>

typedef __bf16 bf16x8 __attribute__((ext_vector_type(8)));
typedef unsigned short u16x8 __attribute__((ext_vector_type(8)));
typedef float f32x4 __attribute__((ext_vector_type(4)));

namespace {
constexpr int kB   = 32;
constexpr int kC   = 64;
constexpr int kT   = 8192;
constexpr int kOUT = 129;
constexpr int kKK  = 1024;   // K*K
constexpr int kNKC = 8;      // k-chunks in phase GEMM (128 f each)
constexpr int kOP  = 144;    // o rows padded to 144 (9 m-tiles, guard-free loads)
}

__device__ inline float sin2pi(float r) {  // r in revolutions, [0,1)
  float o; asm("v_sin_f32 %0, %1" : "=v"(o) : "v"(r)); return o;
}
__device__ inline float cos2pi(float r) {
  float o; asm("v_cos_f32 %0, %1" : "=v"(o) : "v"(r)); return o;
}
__device__ inline unsigned short f2bf_rne(float f) {
  unsigned int u = __builtin_bit_cast(unsigned int, f);
  return (unsigned short)((u + 0x7fffu + ((u >> 16) & 1u)) >> 16);
}
__device__ inline float bf2f(unsigned short h) {
  return __builtin_bit_cast(float, (unsigned int)h << 16);
}
__device__ inline void split8(const float* v, bf16x8& hi, bf16x8& lo) {
  u16x8 h, l;
#pragma unroll
  for (int j = 0; j < 8; ++j) {
    const unsigned short hh = f2bf_rne(v[j]);
    h[j] = hh;
    l[j] = f2bf_rne(v[j] - bf2f(hh));
  }
  hi = __builtin_bit_cast(bf16x8, h);
  lo = __builtin_bit_cast(bf16x8, l);
}
__device__ inline bf16x8 ldbf8(const unsigned short* p) {
  return __builtin_bit_cast(bf16x8, *reinterpret_cast<const u16x8*>(p));
}

// ---------------------------------------------------------------------------
// K0z: split z -> bf16 hi/lo, layout [fb=0..127][o=0..143][fj=0..7]
// ---------------------------------------------------------------------------
__global__ __launch_bounds__(256) void sa_split_z(
    const float* __restrict__ z_real, const float* __restrict__ z_imag,
    unsigned short* __restrict__ zrh, unsigned short* __restrict__ zrl,
    unsigned short* __restrict__ zih, unsigned short* __restrict__ zil)
{
  const int i = blockIdx.x * 256 + threadIdx.x;
  if (i >= 128 * kOP * 8) return;
  const int fj = i & 7;
  const int o  = (i >> 3) % kOP;
  const int fb = i / (kOP * 8);
  const int f  = fb * 8 + fj;
  float vr = 0.f, vi = 0.f;
  if (o < kOUT) {
    vr = z_real[(size_t)o * kKK + f];
    vi = z_imag[(size_t)o * kKK + f];
  }
  unsigned short h = f2bf_rne(vr);
  zrh[i] = h; zrl[i] = f2bf_rne(vr - bf2f(h));
  h = f2bf_rne(vi);
  zih[i] = h; zil[i] = f2bf_rne(vi - bf2f(h));
}

// ---------------------------------------------------------------------------
// K0c: materialize split-bf16 cis tables, layout [b][fb=0..127][c=0..63][fj].
// ---------------------------------------------------------------------------
__global__ __launch_bounds__(256) void sa_cis(
    const float* __restrict__ positions,
    unsigned short* __restrict__ csh, unsigned short* __restrict__ csl,
    unsigned short* __restrict__ snh, unsigned short* __restrict__ snl)
{
  const int i = blockIdx.x * 256 + threadIdx.x;   // < 2097152
  const int fj = i & 7;
  const int c  = (i >> 3) & 63;
  const int fb = (i >> 9) & 127;
  const int b  = i >> 16;
  const int f  = fb * 8 + fj;
  const float2 p = reinterpret_cast<const float2*>(positions)[b * kC + c];
  const float kf = (float)((f & 31) + 1);   // coef_k = (f % 32) + 1
  const float lf = (float)((f >> 5) + 1);   // coef_l = (f / 32) + 1
  const float w = __fadd_rn(__fmul_rn(p.x, kf), __fmul_rn(p.y, lf));
  const float r = w - floorf(w);
  const float cs = cos2pi(r);
  const float sn = sin2pi(r);
  unsigned short h = f2bf_rne(cs);
  csh[i] = h; csl[i] = f2bf_rne(cs - bf2f(h));
  h = f2bf_rne(sn);
  snh[i] = h; snl[i] = f2bf_rne(sn - bf2f(h));
}

// ---------------------------------------------------------------------------
// K1: part[kc][b][o][c] via pure bf16 MFMA (split hi/lo, lo*lo dropped).
// ---------------------------------------------------------------------------
__global__ __launch_bounds__(256) void sa_phase_gemm(
    const unsigned short* __restrict__ zrh, const unsigned short* __restrict__ zrl,
    const unsigned short* __restrict__ zih, const unsigned short* __restrict__ zil,
    const unsigned short* __restrict__ csh, const unsigned short* __restrict__ csl,
    const unsigned short* __restrict__ snh, const unsigned short* __restrict__ snl,
    float* __restrict__ part)
{
  const int bid = blockIdx.x;
  const int b   = bid & 31;
  const int kc  = (bid >> 5) & 7;
  const int mh  = bid >> 8;
  const int w    = threadIdx.x >> 6;
  const int lane = threadIdx.x & 63;
  const int cg   = lane >> 4;
  const int cl   = lane & 15;
  const int c    = w * 16 + cl;

  bf16x8 BcH[4], BcL[4], BsH[4], BsL[4];
#pragma unroll
  for (int ks = 0; ks < 4; ++ks) {
    const size_t off = ((size_t)(b * 128 + kc * 16 + ks * 4 + cg) * kC + c) * 8;
    BcH[ks] = ldbf8(csh + off);
    BcL[ks] = ldbf8(csl + off);
    BsH[ks] = ldbf8(snh + off);
    BsL[ks] = ldbf8(snl + off);
  }

  const int nm  = mh ? 4 : 5;
  const int ob0 = mh * 80;

#pragma unroll
  for (int m = 0; m < 5; ++m) {
    if (m < nm) {
      const int ob = ob0 + m * 16;
      const int oa = ob + cl;
      f32x4 acc = {0.f, 0.f, 0.f, 0.f};
#pragma unroll
      for (int ks = 0; ks < 4; ++ks) {
        const size_t zo = ((size_t)(kc * 16 + ks * 4 + cg) * kOP + oa) * 8;
        const bf16x8 ArH = ldbf8(zrh + zo);
        const bf16x8 ArL = ldbf8(zrl + zo);
        const bf16x8 AiH = ldbf8(zih + zo);
        const bf16x8 AiL = ldbf8(zil + zo);
        acc = __builtin_amdgcn_mfma_f32_16x16x32_bf16(ArH, BcH[ks], acc, 0, 0, 0);
        acc = __builtin_amdgcn_mfma_f32_16x16x32_bf16(ArH, BcL[ks], acc, 0, 0, 0);
        acc = __builtin_amdgcn_mfma_f32_16x16x32_bf16(ArL, BcH[ks], acc, 0, 0, 0);
        acc = __builtin_amdgcn_mfma_f32_16x16x32_bf16(AiH, BsH[ks], acc, 0, 0, 0);
        acc = __builtin_amdgcn_mfma_f32_16x16x32_bf16(AiH, BsL[ks], acc, 0, 0, 0);
        acc = __builtin_amdgcn_mfma_f32_16x16x32_bf16(AiL, BsH[ks], acc, 0, 0, 0);
      }
#pragma unroll
      for (int r = 0; r < 4; ++r) {
        const int o = ob + cg * 4 + r;
        if (o < kOUT)
          part[(((size_t)kc * kB + b) * kOUT + o) * kC + c] = acc[r];
      }
    }
  }
}

// ---------------------------------------------------------------------------
// K2: reduce partials, mask, softmax, emit split-bf16 attn into padded
// [b][144][64] (rows 129..143 zeroed every launch).
// ---------------------------------------------------------------------------
__global__ __launch_bounds__(256) void sa_softmax(
    const float* __restrict__ part,
    const float* __restrict__ positions,
    const int*   __restrict__ drop_idx,
    unsigned short* __restrict__ a_hi,
    unsigned short* __restrict__ a_lo)
{
  const int bop = blockIdx.x * 4 + (threadIdx.x >> 6);  // < 32*144
  const int b  = bop / kOP;
  const int o  = bop - b * kOP;
  const int c  = threadIdx.x & 63;

  if (o >= kOUT) {
    a_hi[(size_t)bop * kC + c] = 0;
    a_lo[(size_t)bop * kC + c] = 0;
    return;
  }

  float a = 0.f;
#pragma unroll
  for (int fc = 0; fc < kNKC; ++fc)
    a += part[(((size_t)fc * kB + b) * kOUT + o) * kC + c];

  const float2 p  = reinterpret_cast<const float2*>(positions)[b * kC + c];
  const int    di = drop_idx[b];
  const float2 pd = reinterpret_cast<const float2*>(positions)[b * kC + di];
  const float dx = p.x - pd.x;
  const float dy = p.y - pd.y;
  const float d2 = __fadd_rn(__fmul_rn(dx, dx), __fmul_rn(dy, dy));
  if (d2 < 0.1f) a = -1e9f;

  float m = a;
#pragma unroll
  for (int off = 32; off; off >>= 1) m = fmaxf(m, __shfl_xor(m, off));
  const float e = expf(a - m);
  float s = e;
#pragma unroll
  for (int off = 32; off; off >>= 1) s += __shfl_xor(s, off);

  const float att = e / s;
  const unsigned short h = f2bf_rne(att);
  a_hi[(size_t)bop * kC + c] = h;
  a_lo[(size_t)bop * kC + c] = f2bf_rne(att - bf2f(h));
}

// ---------------------------------------------------------------------------
// K3: out = attn @ X via bf16 MFMA, WRITE-CONTIGUITY-FIRST.
// Block = (b, 256-t chunk), 512 threads = 8 waves, each wave 2 n-tiles.
// 3 groups of 3 m-tiles: compute 48 o-rows -> stage in LDS [48][260] f32
// (2-way banks on write) -> barrier -> waves store FULL 1KB-contiguous rows
// (ds_read_b128 + global_store_dwordx4, 64 lanes = 1024B per instr).
// This replaces r9's 4x64B scattered segments per store; bytes unchanged,
// HBM write efficiency is the target. A-frags from global (L2-resident).
// ---------------------------------------------------------------------------
__global__ __launch_bounds__(512) void sa_apply_mfma(
    const float* __restrict__ X,
    const unsigned short* __restrict__ a_hi,   // [b][144][64]
    const unsigned short* __restrict__ a_lo,
    float* __restrict__ out)
{
  __shared__ float s_out[48 * 260];   // 49,920 B

  const int b    = blockIdx.x >> 5;
  const int tc   = blockIdx.x & 31;
  const int t0   = tc * 256;
  const int wave = threadIdx.x >> 6;
  const int lane = threadIdx.x & 63;
  const int cl   = lane & 15;
  const int cg   = lane >> 4;
  const int tw   = wave * 32;          // wave's t-offset within the 256 chunk

  // X frags for this wave's 2 n-tiles (split bf16)
  const float* Xb = X + (size_t)b * kC * kT;
  bf16x8 Xh[2][2], Xl[2][2];
#pragma unroll
  for (int n = 0; n < 2; ++n) {
    const int t = t0 + tw + n * 16 + cl;
    float xv[16];
#pragma unroll
    for (int s2 = 0; s2 < 2; ++s2)
#pragma unroll
      for (int j = 0; j < 8; ++j)
        xv[s2 * 8 + j] = Xb[(size_t)(s2 * 32 + cg * 8 + j) * kT + t];
    split8(xv,     Xh[n][0], Xl[n][0]);
    split8(xv + 8, Xh[n][1], Xl[n][1]);
  }

  const unsigned short* Ah = a_hi + (size_t)b * kOP * kC;
  const unsigned short* Al = a_lo + (size_t)b * kOP * kC;
  float* outb = out + (size_t)b * kOUT * kT;

  for (int g = 0; g < 3; ++g) {
    f32x4 acc[3][2];
#pragma unroll
    for (int i = 0; i < 3; ++i) {
      const int row = (g * 3 + i) * 16 + cl;     // A row (padded, guard-free)
      const size_t ra = (size_t)row * kC + cg * 8;
      const bf16x8 Ah0 = ldbf8(Ah + ra);
      const bf16x8 Ah1 = ldbf8(Ah + ra + 32);
      const bf16x8 Al0 = ldbf8(Al + ra);
      const bf16x8 Al1 = ldbf8(Al + ra + 32);
#pragma unroll
      for (int n = 0; n < 2; ++n) {
        f32x4 a4 = {0.f, 0.f, 0.f, 0.f};
        a4 = __builtin_amdgcn_mfma_f32_16x16x32_bf16(Ah0, Xh[n][0], a4, 0, 0, 0);
        a4 = __builtin_amdgcn_mfma_f32_16x16x32_bf16(Ah1, Xh[n][1], a4, 0, 0, 0);
        a4 = __builtin_amdgcn_mfma_f32_16x16x32_bf16(Al0, Xh[n][0], a4, 0, 0, 0);
        a4 = __builtin_amdgcn_mfma_f32_16x16x32_bf16(Al1, Xh[n][1], a4, 0, 0, 0);
        a4 = __builtin_amdgcn_mfma_f32_16x16x32_bf16(Ah0, Xl[n][0], a4, 0, 0, 0);
        a4 = __builtin_amdgcn_mfma_f32_16x16x32_bf16(Ah1, Xl[n][1], a4, 0, 0, 0);
        acc[i][n] = a4;
      }
    }

    // stage into LDS: o_local = i*16 + cg*4 + r, t_local = tw + n*16 + cl
#pragma unroll
    for (int i = 0; i < 3; ++i)
#pragma unroll
      for (int n = 0; n < 2; ++n)
#pragma unroll
        for (int r = 0; r < 4; ++r)
          s_out[(i * 16 + cg * 4 + r) * 260 + tw + n * 16 + cl] = acc[i][n][r];

    __syncthreads();

    // contiguous row stores: 1 KB per instruction
    const int nrows = (g < 2) ? 48 : 33;   // group 2: rows 96..128 valid
    for (int row = wave; row < nrows; row += 8) {
      const float4 v = *reinterpret_cast<const float4*>(&s_out[row * 260 + 4 * lane]);
      *reinterpret_cast<float4*>(&outb[(size_t)(g * 48 + row) * kT + t0 + 4 * lane]) = v;
    }

    __syncthreads();
  }
}

// ---------------------------------------------------------------------------
extern "C" void kernel_launch(void* const* d_in, const int* in_sizes, int n_in,
                              void* d_out, int out_size, void* d_ws, size_t ws_size,
                              hipStream_t stream) {
  (void)in_sizes; (void)n_in; (void)out_size; (void)ws_size;
  const float* X         = (const float*)d_in[0];
  const float* positions = (const float*)d_in[1];
  const int*   drop_idx  = (const int*)d_in[2];
  const float* z_real    = (const float*)d_in[3];
  const float* z_imag    = (const float*)d_in[4];
  float* out = (float*)d_out;

  // workspace layout (~27.7 MB)
  char* wsb = (char*)d_ws;
  float* part = (float*)wsb;                                    // 8,454,144 B
  unsigned short* ahi = (unsigned short*)(wsb + 8454144);       // [32][144][64]
  unsigned short* alo = ahi + (size_t)kB * kOP * kC;
  unsigned short* zrh = alo + (size_t)kB * kOP * kC;
  unsigned short* zrl = zrh + 147456;
  unsigned short* zih = zrl + 147456;
  unsigned short* zil = zih + 147456;
  unsigned short* csh = zil + 147456;
  unsigned short* csl = csh + 2097152;
  unsigned short* snh = csl + 2097152;
  unsigned short* snl = snh + 2097152;

  sa_split_z<<<576, 256, 0, stream>>>(z_real, z_imag, zrh, zrl, zih, zil);
  sa_cis<<<8192, 256, 0, stream>>>(positions, csh, csl, snh, snl);
  sa_phase_gemm<<<kB * kNKC * 2, 256, 0, stream>>>(zrh, zrl, zih, zil,
                                                   csh, csl, snh, snl, part);
  sa_softmax<<<kB * kOP / 4, 256, 0, stream>>>(part, positions, drop_idx, ahi, alo);
  sa_apply_mfma<<<kB * 32, 512, 0, stream>>>(X, ahi, alo, out);
}